// Round 9
// baseline (198.450 us; speedup 1.0000x reference)
//
#include <hip/hip_runtime.h>

typedef __attribute__((ext_vector_type(8))) short bf16x8;
typedef __attribute__((ext_vector_type(4))) short bf16x4;
typedef __attribute__((ext_vector_type(4))) float f32x4;

#define MFMA(a, b, c) __builtin_amdgcn_mfma_f32_16x16x32_bf16(a, b, c, 0, 0, 0)
#define MFMA16(a, b, c) __builtin_amdgcn_mfma_f32_16x16x16bf16_1k(a, b, c, 0, 0, 0)

__device__ __forceinline__ unsigned short f2bf(float f) {
    unsigned u = __builtin_bit_cast(unsigned, f);
    u += 0x7fffu + ((u >> 16) & 1u);
    return (unsigned short)(u >> 16);
}

// async global->LDS DMA, 16B per lane; hardware writes lane i's data at
// (wave-uniform) lds base + i*16B. gptr is per-lane.
__device__ __forceinline__ void gload16(const unsigned short* g, unsigned short* l) {
    __builtin_amdgcn_global_load_lds(
        (const __attribute__((address_space(1))) void*)g,
        (__attribute__((address_space(3))) void*)l, 16, 0, 0);
}

// pack two fp32 -> two bf16 (round-half-up) in one uint via v_perm_b32
__device__ __forceinline__ unsigned pack_bf16(float lo, float hi) {
    unsigned a = __builtin_bit_cast(unsigned, lo) + 0x8000u;
    unsigned b = __builtin_bit_cast(unsigned, hi) + 0x8000u;
    return __builtin_amdgcn_perm(b, a, 0x07060302);  // [hi16(b) : hi16(a)]
}

// ---------------- pass A: convert / transpose / rope tables ----------------

__global__ __launch_bounds__(256) void cvt_bf16(const float* __restrict__ in,
                                                unsigned short* __restrict__ out, int n) {
    int i = (blockIdx.x * 256 + threadIdx.x) * 4;
    if (i < n) {
        float4 f = *(const float4*)(in + i);
        ushort4 u;
        u.x = f2bf(f.x); u.y = f2bf(f.y); u.z = f2bf(f.z); u.w = f2bf(f.w);
        *(ushort4*)(out + i) = u;
    }
}

// in: [R, C] fp32 row-major  ->  out: [C, R] bf16 row-major
__global__ __launch_bounds__(256) void transpose_cvt(const float* __restrict__ in,
                                                     unsigned short* __restrict__ out,
                                                     int R, int C) {
    __shared__ float tile[32][33];
    const int c0 = blockIdx.x * 32, r0 = blockIdx.y * 32;
    const int tr = threadIdx.x >> 3;
    const int j4 = (threadIdx.x & 7) * 4;
    float4 f = *(const float4*)(in + (size_t)(r0 + tr) * C + c0 + j4);
    tile[tr][j4 + 0] = f.x; tile[tr][j4 + 1] = f.y;
    tile[tr][j4 + 2] = f.z; tile[tr][j4 + 3] = f.w;
    __syncthreads();
    ushort4 u;
    u.x = f2bf(tile[j4 + 0][tr]); u.y = f2bf(tile[j4 + 1][tr]);
    u.z = f2bf(tile[j4 + 2][tr]); u.w = f2bf(tile[j4 + 3][tr]);
    *(ushort4*)(out + (size_t)(c0 + tr) * R + r0 + j4) = u;
}

// accurate RoPE tables (libm sincosf: proper range reduction; v_sin_f32 is
// undefined past +-256 revolutions)
__global__ __launch_bounds__(256) void rope_tab(float* __restrict__ cosT,
                                                float* __restrict__ sinT) {
    int i = blockIdx.x * 256 + threadIdx.x;       // 2048*32 = 65536
    int n = i >> 5, f = i & 31;
    float ang = (float)n * exp2f((float)f * -0.4152410118609203f);
    float s, c;
    sincosf(ang, &s, &c);
    cosT[i] = c; sinT[i] = s;
}

// ---------------- GEMM (A [M,K] bf16) x (Bt [N,K] bf16) ----------------
// m97-style: global_load_lds width-16 staging, LDS double buffer, ONE barrier
// per K-iter. (unchanged from R8 - verified)

template <int EPI>
__global__ __launch_bounds__(256, 3) void gemm_bt(const unsigned short* __restrict__ A,
                                                  const unsigned short* __restrict__ Bt,
                                                  int K, int Ncols,
                                                  unsigned short* __restrict__ oq,
                                                  unsigned short* __restrict__ ok,
                                                  unsigned short* __restrict__ ovt,
                                                  float* __restrict__ of,
                                                  const float* __restrict__ cosT,
                                                  const float* __restrict__ sinT) {
    __shared__ unsigned short As[2][128 * 32];
    __shared__ unsigned short Bs[2][128 * 32];
    const int tid = threadIdx.x;
    const int w = tid >> 6, lane = tid & 63, quad = lane >> 4, cc = lane & 15;
    const int wm = w >> 1, wn = w & 1;
    const int m0 = blockIdx.y * 128, n0 = blockIdx.x * 128;

    size_t aoff[2], boff[2];
#pragma unroll
    for (int t = 0; t < 2; t++) {
        int S = w * 128 + t * 64 + lane;
        int row = S >> 2;
        int c = (S & 3) ^ ((row >> 1) & 3);
        aoff[t] = (size_t)(m0 + row) * K + c * 8;
        boff[t] = (size_t)(n0 + row) * K + c * 8;
    }

    // prime buffer 0
#pragma unroll
    for (int t = 0; t < 2; t++) {
        gload16(A + aoff[t], &As[0][(w * 2 + t) * 512]);
        gload16(Bt + boff[t], &Bs[0][(w * 2 + t) * 512]);
    }
    __syncthreads();

    f32x4 acc[4][4] = {};
    const int rpos = (quad ^ ((cc >> 1) & 3)) * 8;   // swizzled chunk offset (shorts)
    const int nkt = K >> 5;

    for (int kt = 0; kt < nkt; kt++) {
        const int pb = kt & 1;
        if (kt < nkt - 1) {
            const int ko = (kt + 1) * 32;
#pragma unroll
            for (int t = 0; t < 2; t++) {
                gload16(A + aoff[t] + ko, &As[pb ^ 1][(w * 2 + t) * 512]);
                gload16(Bt + boff[t] + ko, &Bs[pb ^ 1][(w * 2 + t) * 512]);
            }
        }
        bf16x8 af[4], bf[4];
#pragma unroll
        for (int i = 0; i < 4; i++)
            af[i] = *(const bf16x8*)&As[pb][(wm * 64 + i * 16 + cc) * 32 + rpos];
#pragma unroll
        for (int i = 0; i < 4; i++)
            bf[i] = *(const bf16x8*)&Bs[pb][(wn * 64 + i * 16 + cc) * 32 + rpos];
#pragma unroll
        for (int i = 0; i < 4; i++)
#pragma unroll
            for (int j = 0; j < 4; j++)
                acc[i][j] = MFMA(af[i], bf[j], acc[i][j]);
        __syncthreads();   // drains this iter's DMA + guards buffer swap
    }

    if (EPI == 0) {
        const int e0 = n0 + wn * 64;
        const int which = e0 >> 10;           // 0=q 1=k 2=v
        const int h = (e0 >> 6) & 15;
        if (which < 2) {
            unsigned short* dst = (which == 0) ? oq : ok;
            const float postscale = (which == 0) ? 0.125f : 1.0f;
#pragma unroll
            for (int mf = 0; mf < 4; mf++) {
#pragma unroll
                for (int r = 0; r < 4; r++) {
                    int mg = m0 + wm * 64 + mf * 16 + quad * 4 + r;
                    int nseq = mg & 2047, b = mg >> 11;
                    float vals[4];
#pragma unroll
                    for (int nf = 0; nf < 4; nf++) vals[nf] = acc[mf][nf][r];
                    size_t rowbase = ((size_t)(b * 16 + h) * 2048 + nseq) * 64;
#pragma unroll
                    for (int nf = 0; nf < 4; nf++) {
                        int d = nf * 16 + cc;
                        int f = d & 31;
                        float cs = cosT[nseq * 32 + f];
                        float sn = sinT[nseq * 32 + f];
                        float partner = vals[nf ^ 2];
                        float outv = (vals[nf] * cs +
                                      ((nf < 2) ? -partner : partner) * sn) * postscale;
                        dst[rowbase + d] = f2bf(outv);
                    }
                }
            }
        } else {
#pragma unroll
            for (int mf = 0; mf < 4; mf++) {
                int mg0 = m0 + wm * 64 + mf * 16 + quad * 4;
                int b = mg0 >> 11, nseq = mg0 & 2047;
#pragma unroll
                for (int nf = 0; nf < 4; nf++) {
                    int d = nf * 16 + cc;
                    ushort4 pk;
                    pk.x = f2bf(acc[mf][nf][0]);
                    pk.y = f2bf(acc[mf][nf][1]);
                    pk.z = f2bf(acc[mf][nf][2]);
                    pk.w = f2bf(acc[mf][nf][3]);
                    *(ushort4*)(ovt + ((size_t)(b * 16 + h) * 64 + d) * 2048 + nseq) = pk;
                }
            }
        }
    } else {
#pragma unroll
        for (int mf = 0; mf < 4; mf++)
#pragma unroll
            for (int nf = 0; nf < 4; nf++)
#pragma unroll
                for (int r = 0; r < 4; r++) {
                    int mg = m0 + wm * 64 + mf * 16 + quad * 4 + r;
                    of[(size_t)mg * Ncols + n0 + wn * 64 + nf * 16 + cc] = acc[mf][nf][r];
                }
    }
}

// ---------------- flash attention v4: P stays in registers ----------------
// q,k: [B,H,N,D] bf16 (q pre-scaled by 1/8); vt: [B,H,D,N] bf16; o: [B,N,H*D] bf16
// QK as S^T (verified R8): s2[mf][nf] reg r = S[m=cc][n=nf*16+quad*4+r].
// Packed pk{bf16(p0,p1),bf16(p2,p3)} = P[m=cc][k=quad*4+j] == the EXACT
// B-operand fragment of mfma_f32_16x16x16bf16_1k -> PV consumes P straight
// from registers (no LDS transpose). First operand = V^T rows (A-operand,
// [d=cc][k=quad*4+j], b64 reads) -> output lands as O^T: lane holds
// O[m=cc][d=quad*4+r], so the row-sum divisor rs (indexed m=cc) is in-lane
// and the epilogue is packed dwordx2 global stores. ps/rsb buffers deleted:
// LDS = ks+vs = 32KB exactly -> 4 blocks/CU (usable LDS ~128KB, R2/R4/R7 data).

__global__ __launch_bounds__(256, 4) void attn(const unsigned short* __restrict__ q,
                                               const unsigned short* __restrict__ k,
                                               const unsigned short* __restrict__ vt,
                                               unsigned short* __restrict__ o) {
    __shared__ unsigned short ks[2][64 * 64];
    __shared__ unsigned short vs[2][64 * 64];
    const int tid = threadIdx.x;
    const int w = tid >> 6, lane = tid & 63, quad = lane >> 4, cc = lane & 15;
    const int bh = blockIdx.x & 31, qt = blockIdx.x >> 5;

    // Q fragments -> registers (A-layout: lane(quad,cc) holds Q[m=cc][k=quad*8+j])
    const unsigned short* qg = q + ((size_t)bh * 2048 + qt * 128 + w * 32) * 64;
    bf16x8 aq[2][2];
#pragma unroll
    for (int mf = 0; mf < 2; mf++)
#pragma unroll
        for (int kc = 0; kc < 2; kc++)
            aq[mf][kc] = *(const bf16x8*)(qg + (mf * 16 + cc) * 64 + kc * 32 + quad * 8);

    // DMA source offsets: wave w covers slots [w*128, w*128+128), 2 calls.
    // Slot S -> row=S>>3, fetches global chunk (S&7)^(row&7) (XOR bank swizzle).
    int koff[2], voff[2];
#pragma unroll
    for (int t = 0; t < 2; t++) {
        int S = w * 128 + t * 64 + lane;
        int row = S >> 3;
        int c = (S & 7) ^ (row & 7);
        koff[t] = row * 64 + c * 8;       // k rows: stride 64 shorts
        voff[t] = row * 2048 + c * 8;     // vt rows: stride 2048 shorts
    }

    const unsigned short* kg0 = k + (size_t)bh * 2048 * 64;
    const unsigned short* vg0 = vt + (size_t)bh * 64 * 2048;

    // prime buffer 0 with tile 0
#pragma unroll
    for (int t = 0; t < 2; t++) {
        gload16(kg0 + koff[t], &ks[0][(w * 2 + t) * 512]);
        gload16(vg0 + voff[t], &vs[0][(w * 2 + t) * 512]);
    }
    __syncthreads();

    f32x4 oacc[2][4] = {};   // O^T: oacc[mf][df] reg r = O[m=cc][d=df*16+quad*4+r]
    float rs[2] = {};

    for (int kt = 0; kt < 32; kt++) {
        const int pb = kt & 1;
        if (kt < 31) {     // DMA next tile into idle buffer; drains at loop-end barrier
            const unsigned short* kb = kg0 + (kt + 1) * 4096;
            const unsigned short* vb = vg0 + (kt + 1) * 64;
#pragma unroll
            for (int t = 0; t < 2; t++) {
                gload16(kb + koff[t], &ks[pb ^ 1][(w * 2 + t) * 512]);
                gload16(vb + voff[t], &vs[pb ^ 1][(w * 2 + t) * 512]);
            }
        }

        // S^T = MFMA(K-rows, Q-rows): s2[mf][nf] reg r = S[m=cc][n=nf*16+quad*4+r]
        f32x4 s2[2][4] = {};
#pragma unroll
        for (int kc = 0; kc < 2; kc++) {
#pragma unroll
            for (int nf = 0; nf < 4; nf++) {
                bf16x8 bk = *(const bf16x8*)&ks[pb][(nf * 16 + cc) * 64 +
                                                    ((kc * 4 + quad) ^ (cc & 7)) * 8];
                s2[0][nf] = MFMA(bk, aq[0][kc], s2[0][nf]);
                s2[1][nf] = MFMA(bk, aq[1][kc], s2[1][nf]);
            }
        }

        // p = exp(s - 8); in-lane row-sums; pack into K=16 B-operand fragments
        bf16x4 pkr[2][4];
#pragma unroll
        for (int mf = 0; mf < 2; mf++) {
#pragma unroll
            for (int nf = 0; nf < 4; nf++) {
                float p0 = __builtin_amdgcn_exp2f(
                    __builtin_fmaf(s2[mf][nf][0], 1.44269504f, -11.54156036f));
                float p1 = __builtin_amdgcn_exp2f(
                    __builtin_fmaf(s2[mf][nf][1], 1.44269504f, -11.54156036f));
                float p2 = __builtin_amdgcn_exp2f(
                    __builtin_fmaf(s2[mf][nf][2], 1.44269504f, -11.54156036f));
                float p3 = __builtin_amdgcn_exp2f(
                    __builtin_fmaf(s2[mf][nf][3], 1.44269504f, -11.54156036f));
                rs[mf] += (p0 + p1) + (p2 + p3);
                uint2 u;
                u.x = pack_bf16(p0, p1);
                u.y = pack_bf16(p2, p3);
                pkr[mf][nf] = __builtin_bit_cast(bf16x4, u);
            }
        }

        // O^T += V^T x P^T via K=16 MFMA; P straight from registers.
        // bv16 = V^T[d=cc within df-tile][n=nf*16+quad*4+j] (b64, swizzle-adjusted)
#pragma unroll
        for (int nf = 0; nf < 4; nf++) {
#pragma unroll
            for (int df = 0; df < 4; df++) {
                bf16x4 bv = *(const bf16x4*)&vs[pb][(df * 16 + cc) * 64 +
                                                    (((nf * 2 + (quad >> 1)) ^ (cc & 7)) * 8) +
                                                    (quad & 1) * 4];
                oacc[0][df] = MFMA16(bv, pkr[0][nf], oacc[0][df]);
                oacc[1][df] = MFMA16(bv, pkr[1][nf], oacc[1][df]);
            }
        }

        __syncthreads();   // drains this iter's DMA (vmcnt) + guards buffer swap
    }

    // row-sum: reduce over the 4 quads (all hold partial sums for row m=cc)
#pragma unroll
    for (int mf = 0; mf < 2; mf++) {
        rs[mf] += __shfl_xor(rs[mf], 16, 64);
        rs[mf] += __shfl_xor(rs[mf], 32, 64);
    }

    // epilogue: normalize in-lane, pack, direct global dwordx2 stores
    {
        const int b = bh >> 4, h = bh & 15;
        unsigned short* og = o + ((size_t)(b * 2048 + qt * 128 + w * 32)) * 1024 + h * 64;
#pragma unroll
        for (int mf = 0; mf < 2; mf++) {
            float inv = 1.0f / rs[mf];
#pragma unroll
            for (int df = 0; df < 4; df++) {
                uint2 u;
                u.x = pack_bf16(oacc[mf][df][0] * inv, oacc[mf][df][1] * inv);
                u.y = pack_bf16(oacc[mf][df][2] * inv, oacc[mf][df][3] * inv);
                *(uint2*)(og + (size_t)(mf * 16 + cc) * 1024 + df * 16 + quad * 4) = u;
            }
        }
    }
}

// ---------------- launcher ----------------

extern "C" void kernel_launch(void* const* d_in, const int* in_sizes, int n_in,
                              void* d_out, int out_size, void* d_ws, size_t ws_size,
                              hipStream_t stream) {
    const float* x = (const float*)d_in[0];
    const float* w_qkv = (const float*)d_in[1];
    const float* w_out = (const float*)d_in[2];
    float* out = (float*)d_out;

    unsigned short* xb    = (unsigned short*)d_ws;        // 4096*1024
    unsigned short* wqkvT = xb + 4096 * 1024;             // 3072*1024
    unsigned short* woutT = wqkvT + 3072 * 1024;          // 1024*1024
    unsigned short* qb    = woutT + 1024 * 1024;          // 2*16*2048*64
    unsigned short* kb    = qb + 2 * 16 * 2048 * 64;
    unsigned short* vtb   = kb + 2 * 16 * 2048 * 64;
    unsigned short* ob    = vtb + 2 * 16 * 2048 * 64;     // 4096*1024
    float* cosT = (float*)(ob + 4096 * 1024);             // 2048*32 fp32
    float* sinT = cosT + 2048 * 32;

    rope_tab<<<256, 256, 0, stream>>>(cosT, sinT);
    cvt_bf16<<<4096, 256, 0, stream>>>(x, xb, 4096 * 1024);
    transpose_cvt<<<dim3(96, 32), 256, 0, stream>>>(w_qkv, wqkvT, 1024, 3072);
    transpose_cvt<<<dim3(32, 32), 256, 0, stream>>>(w_out, woutT, 1024, 1024);
    gemm_bt<0><<<dim3(24, 32), 256, 0, stream>>>(xb, wqkvT, 1024, 3072,
                                                 qb, kb, vtb, nullptr, cosT, sinT);
    attn<<<512, 256, 0, stream>>>(qb, kb, vtb, ob);
    gemm_bt<1><<<dim3(8, 32), 256, 0, stream>>>(ob, woutT, 1024, 1024,
                                                nullptr, nullptr, nullptr, out,
                                                nullptr, nullptr);
}

// Round 10
// 191.682 us; speedup vs baseline: 1.0353x; 1.0353x over previous
//
#include <hip/hip_runtime.h>

typedef __attribute__((ext_vector_type(8))) short bf16x8;
typedef __attribute__((ext_vector_type(4))) short bf16x4;
typedef __attribute__((ext_vector_type(4))) float f32x4;

#define MFMA(a, b, c) __builtin_amdgcn_mfma_f32_16x16x32_bf16(a, b, c, 0, 0, 0)
#define MFMA16(a, b, c) __builtin_amdgcn_mfma_f32_16x16x16bf16_1k(a, b, c, 0, 0, 0)

__device__ __forceinline__ unsigned short f2bf(float f) {
    unsigned u = __builtin_bit_cast(unsigned, f);
    u += 0x7fffu + ((u >> 16) & 1u);
    return (unsigned short)(u >> 16);
}

// async global->LDS DMA, 16B per lane; LDS dest = wave-uniform base + lane*16.
__device__ __forceinline__ void gload16(const unsigned short* g, unsigned short* l) {
    __builtin_amdgcn_global_load_lds(
        (const __attribute__((address_space(1))) void*)g,
        (__attribute__((address_space(3))) void*)l, 16, 0, 0);
}

// pack two fp32 -> two bf16, round-half-up (3 VALU)
__device__ __forceinline__ unsigned pack_bf16(float lo, float hi) {
    unsigned a = __builtin_bit_cast(unsigned, lo) + 0x8000u;
    unsigned b = __builtin_bit_cast(unsigned, hi) + 0x8000u;
    return __builtin_amdgcn_perm(b, a, 0x07060302);
}
// truncating pack (1 VALU); ~0.2% downward bias, cancels in O/rs normalization
__device__ __forceinline__ unsigned pack_bf16_trunc(float lo, float hi) {
    return __builtin_amdgcn_perm(__builtin_bit_cast(unsigned, hi),
                                 __builtin_bit_cast(unsigned, lo), 0x07060302);
}

// ---------------- pass A: convert / transpose / rope tables ----------------

__global__ __launch_bounds__(256) void cvt_bf16(const float* __restrict__ in,
                                                unsigned short* __restrict__ out, int n) {
    int i = (blockIdx.x * 256 + threadIdx.x) * 4;
    if (i < n) {
        float4 f = *(const float4*)(in + i);
        ushort4 u;
        u.x = f2bf(f.x); u.y = f2bf(f.y); u.z = f2bf(f.z); u.w = f2bf(f.w);
        *(ushort4*)(out + i) = u;
    }
}

__global__ __launch_bounds__(256) void transpose_cvt(const float* __restrict__ in,
                                                     unsigned short* __restrict__ out,
                                                     int R, int C) {
    __shared__ float tile[32][33];
    const int c0 = blockIdx.x * 32, r0 = blockIdx.y * 32;
    const int tr = threadIdx.x >> 3;
    const int j4 = (threadIdx.x & 7) * 4;
    float4 f = *(const float4*)(in + (size_t)(r0 + tr) * C + c0 + j4);
    tile[tr][j4 + 0] = f.x; tile[tr][j4 + 1] = f.y;
    tile[tr][j4 + 2] = f.z; tile[tr][j4 + 3] = f.w;
    __syncthreads();
    ushort4 u;
    u.x = f2bf(tile[j4 + 0][tr]); u.y = f2bf(tile[j4 + 1][tr]);
    u.z = f2bf(tile[j4 + 2][tr]); u.w = f2bf(tile[j4 + 3][tr]);
    *(ushort4*)(out + (size_t)(c0 + tr) * R + r0 + j4) = u;
}

__global__ __launch_bounds__(256) void rope_tab(float* __restrict__ cosT,
                                                float* __restrict__ sinT) {
    int i = blockIdx.x * 256 + threadIdx.x;       // 2048*32
    int n = i >> 5, f = i & 31;
    float ang = (float)n * exp2f((float)f * -0.4152410118609203f);
    float s, c;
    sincosf(ang, &s, &c);
    cosT[i] = c; sinT[i] = s;
}

// ---------------- GEMM (A [M,K] bf16) x (Bt [N,K] bf16) ----------------
// m97-style staging (R8-verified). EPI0: RoPE epilogue; q scaled by
// 0.125*log2e (both the 1/sqrt(d) softmax scale AND exp->exp2 conversion
// folded in; the exp2 bias constant cancels in O/rs).

template <int EPI>
__global__ __launch_bounds__(256, 3) void gemm_bt(const unsigned short* __restrict__ A,
                                                  const unsigned short* __restrict__ Bt,
                                                  int K, int Ncols,
                                                  unsigned short* __restrict__ oq,
                                                  unsigned short* __restrict__ ok,
                                                  unsigned short* __restrict__ ovt,
                                                  float* __restrict__ of,
                                                  const float* __restrict__ cosT,
                                                  const float* __restrict__ sinT) {
    __shared__ unsigned short As[2][128 * 32];
    __shared__ unsigned short Bs[2][128 * 32];
    const int tid = threadIdx.x;
    const int w = tid >> 6, lane = tid & 63, quad = lane >> 4, cc = lane & 15;
    const int wm = w >> 1, wn = w & 1;
    const int m0 = blockIdx.y * 128, n0 = blockIdx.x * 128;

    size_t aoff[2], boff[2];
#pragma unroll
    for (int t = 0; t < 2; t++) {
        int S = w * 128 + t * 64 + lane;
        int row = S >> 2;
        int c = (S & 3) ^ ((row >> 1) & 3);
        aoff[t] = (size_t)(m0 + row) * K + c * 8;
        boff[t] = (size_t)(n0 + row) * K + c * 8;
    }

#pragma unroll
    for (int t = 0; t < 2; t++) {
        gload16(A + aoff[t], &As[0][(w * 2 + t) * 512]);
        gload16(Bt + boff[t], &Bs[0][(w * 2 + t) * 512]);
    }
    __syncthreads();

    f32x4 acc[4][4] = {};
    const int rpos = (quad ^ ((cc >> 1) & 3)) * 8;
    const int nkt = K >> 5;

    for (int kt = 0; kt < nkt; kt++) {
        const int pb = kt & 1;
        if (kt < nkt - 1) {
            const int ko = (kt + 1) * 32;
#pragma unroll
            for (int t = 0; t < 2; t++) {
                gload16(A + aoff[t] + ko, &As[pb ^ 1][(w * 2 + t) * 512]);
                gload16(Bt + boff[t] + ko, &Bs[pb ^ 1][(w * 2 + t) * 512]);
            }
        }
        bf16x8 af[4], bf[4];
#pragma unroll
        for (int i = 0; i < 4; i++)
            af[i] = *(const bf16x8*)&As[pb][(wm * 64 + i * 16 + cc) * 32 + rpos];
#pragma unroll
        for (int i = 0; i < 4; i++)
            bf[i] = *(const bf16x8*)&Bs[pb][(wn * 64 + i * 16 + cc) * 32 + rpos];
#pragma unroll
        for (int i = 0; i < 4; i++)
#pragma unroll
            for (int j = 0; j < 4; j++)
                acc[i][j] = MFMA(af[i], bf[j], acc[i][j]);
        __syncthreads();
    }

    if (EPI == 0) {
        const int e0 = n0 + wn * 64;
        const int which = e0 >> 10;           // 0=q 1=k 2=v
        const int h = (e0 >> 6) & 15;
        if (which < 2) {
            unsigned short* dst = (which == 0) ? oq : ok;
            // q: 1/8 softmax scale * log2e (exp->exp2 fold)
            const float postscale = (which == 0) ? 0.18033688f : 1.0f;
#pragma unroll
            for (int mf = 0; mf < 4; mf++) {
#pragma unroll
                for (int r = 0; r < 4; r++) {
                    int mg = m0 + wm * 64 + mf * 16 + quad * 4 + r;
                    int nseq = mg & 2047, b = mg >> 11;
                    float vals[4];
#pragma unroll
                    for (int nf = 0; nf < 4; nf++) vals[nf] = acc[mf][nf][r];
                    size_t rowbase = ((size_t)(b * 16 + h) * 2048 + nseq) * 64;
#pragma unroll
                    for (int nf = 0; nf < 4; nf++) {
                        int d = nf * 16 + cc;
                        int f = d & 31;
                        float cs = cosT[nseq * 32 + f];
                        float sn = sinT[nseq * 32 + f];
                        float partner = vals[nf ^ 2];
                        float outv = (vals[nf] * cs +
                                      ((nf < 2) ? -partner : partner) * sn) * postscale;
                        dst[rowbase + d] = f2bf(outv);
                    }
                }
            }
        } else {
#pragma unroll
            for (int mf = 0; mf < 4; mf++) {
                int mg0 = m0 + wm * 64 + mf * 16 + quad * 4;
                int b = mg0 >> 11, nseq = mg0 & 2047;
#pragma unroll
                for (int nf = 0; nf < 4; nf++) {
                    int d = nf * 16 + cc;
                    ushort4 pk;
                    pk.x = f2bf(acc[mf][nf][0]);
                    pk.y = f2bf(acc[mf][nf][1]);
                    pk.z = f2bf(acc[mf][nf][2]);
                    pk.w = f2bf(acc[mf][nf][3]);
                    *(ushort4*)(ovt + ((size_t)(b * 16 + h) * 64 + d) * 2048 + nseq) = pk;
                }
            }
        }
    } else {
#pragma unroll
        for (int mf = 0; mf < 4; mf++)
#pragma unroll
            for (int nf = 0; nf < 4; nf++)
#pragma unroll
                for (int r = 0; r < 4; r++) {
                    int mg = m0 + wm * 64 + mf * 16 + quad * 4 + r;
                    of[(size_t)mg * Ncols + n0 + wn * 64 + nf * 16 + cc] = acc[mf][nf][r];
                }
    }
}

// ---------------- flash attention v5: split-K halves ----------------
// Fixed-max softmax makes partials LINEAR: O = (O1+O2)/(rs1+rs2) -> each of
// 2 halves runs 16 K-iters over its half of the sequence, writes unnormalized
// bf16 partial O^T + fp32 rs. grid 1024 = 4 blocks/CU (vs 512 = 2: the grid,
// not LDS, was capping occupancy in R9). p' = exp2(s') directly (log2e folded
// into q; exp2 bias constant cancels in the final division).

__global__ __launch_bounds__(256, 4) void attn_half(const unsigned short* __restrict__ q,
                                                    const unsigned short* __restrict__ k,
                                                    const unsigned short* __restrict__ vt,
                                                    unsigned short* __restrict__ opart,
                                                    float* __restrict__ rspart) {
    __shared__ unsigned short ks[2][64 * 64];
    __shared__ unsigned short vs[2][64 * 64];
    const int tid = threadIdx.x;
    const int w = tid >> 6, lane = tid & 63, quad = lane >> 4, cc = lane & 15;
    const int bh = blockIdx.x & 31;
    const int half = (blockIdx.x >> 5) & 1;
    const int qt = blockIdx.x >> 6;

    // Q fragments (A-layout), q pre-scaled by 0.125*log2e
    const unsigned short* qg = q + ((size_t)bh * 2048 + qt * 128 + w * 32) * 64;
    bf16x8 aq[2][2];
#pragma unroll
    for (int mf = 0; mf < 2; mf++)
#pragma unroll
        for (int kc = 0; kc < 2; kc++)
            aq[mf][kc] = *(const bf16x8*)(qg + (mf * 16 + cc) * 64 + kc * 32 + quad * 8);

    int koff[2], voff[2];
#pragma unroll
    for (int t = 0; t < 2; t++) {
        int S = w * 128 + t * 64 + lane;
        int row = S >> 3;
        int c = (S & 7) ^ (row & 7);
        koff[t] = row * 64 + c * 8;
        voff[t] = row * 2048 + c * 8;
    }

    const unsigned short* kg0 = k + (size_t)bh * 2048 * 64 + half * 65536;  // 16 tiles
    const unsigned short* vg0 = vt + (size_t)bh * 64 * 2048 + half * 1024;

#pragma unroll
    for (int t = 0; t < 2; t++) {
        gload16(kg0 + koff[t], &ks[0][(w * 2 + t) * 512]);
        gload16(vg0 + voff[t], &vs[0][(w * 2 + t) * 512]);
    }
    __syncthreads();

    f32x4 oacc[2][4] = {};   // O^T partial: oacc[mf][df] reg r = O[m=cc][d=df*16+quad*4+r]
    float rs[2] = {};

    for (int kt = 0; kt < 16; kt++) {
        const int pb = kt & 1;
        if (kt < 15) {
            const unsigned short* kb = kg0 + (kt + 1) * 4096;
            const unsigned short* vb = vg0 + (kt + 1) * 64;
#pragma unroll
            for (int t = 0; t < 2; t++) {
                gload16(kb + koff[t], &ks[pb ^ 1][(w * 2 + t) * 512]);
                gload16(vb + voff[t], &vs[pb ^ 1][(w * 2 + t) * 512]);
            }
        }

        // S'^T = MFMA(K-rows, Q-rows); s' already includes *log2e/8
        f32x4 s2[2][4] = {};
#pragma unroll
        for (int kc = 0; kc < 2; kc++) {
#pragma unroll
            for (int nf = 0; nf < 4; nf++) {
                bf16x8 bk = *(const bf16x8*)&ks[pb][(nf * 16 + cc) * 64 +
                                                    ((kc * 4 + quad) ^ (cc & 7)) * 8];
                s2[0][nf] = MFMA(bk, aq[0][kc], s2[0][nf]);
                s2[1][nf] = MFMA(bk, aq[1][kc], s2[1][nf]);
            }
        }

        // p' = exp2(s') straight off the MFMA output; truncating pack
        bf16x4 pkr[2][4];
#pragma unroll
        for (int mf = 0; mf < 2; mf++) {
#pragma unroll
            for (int nf = 0; nf < 4; nf++) {
                float p0 = __builtin_amdgcn_exp2f(s2[mf][nf][0]);
                float p1 = __builtin_amdgcn_exp2f(s2[mf][nf][1]);
                float p2 = __builtin_amdgcn_exp2f(s2[mf][nf][2]);
                float p3 = __builtin_amdgcn_exp2f(s2[mf][nf][3]);
                rs[mf] += (p0 + p1) + (p2 + p3);
                uint2 u;
                u.x = pack_bf16_trunc(p0, p1);
                u.y = pack_bf16_trunc(p2, p3);
                pkr[mf][nf] = __builtin_bit_cast(bf16x4, u);
            }
        }

        // O^T += V^T x P^T, P direct from registers (K=16 B-operand layout)
#pragma unroll
        for (int nf = 0; nf < 4; nf++) {
#pragma unroll
            for (int df = 0; df < 4; df++) {
                bf16x4 bv = *(const bf16x4*)&vs[pb][(df * 16 + cc) * 64 +
                                                    (((nf * 2 + (quad >> 1)) ^ (cc & 7)) * 8) +
                                                    (quad & 1) * 4];
                oacc[0][df] = MFMA16(bv, pkr[0][nf], oacc[0][df]);
                oacc[1][df] = MFMA16(bv, pkr[1][nf], oacc[1][df]);
            }
        }

        __syncthreads();
    }

    // reduce rs across the 4 quads (each lane ends with the full half-sum)
#pragma unroll
    for (int mf = 0; mf < 2; mf++) {
        rs[mf] += __shfl_xor(rs[mf], 16, 64);
        rs[mf] += __shfl_xor(rs[mf], 32, 64);
    }

    // store bf16 partial O^T (rounded) + fp32 rs
    {
        unsigned short* op = opart +
            ((size_t)(half * 32 + bh) * 2048 + qt * 128 + w * 32) * 64;
#pragma unroll
        for (int mf = 0; mf < 2; mf++)
#pragma unroll
            for (int df = 0; df < 4; df++) {
                uint2 u;
                u.x = pack_bf16(oacc[mf][df][0], oacc[mf][df][1]);
                u.y = pack_bf16(oacc[mf][df][2], oacc[mf][df][3]);
                *(uint2*)(op + (size_t)(mf * 16 + cc) * 64 + df * 16 + quad * 4) = u;
            }
        if (lane < 16) {
            float* rp = rspart + (size_t)(half * 32 + bh) * 2048 + qt * 128 + w * 32;
            rp[cc] = rs[0];
            rp[16 + cc] = rs[1];
        }
    }
}

// combine: o[b,n,h*64+d] = (O1+O2)/(rs1+rs2), bf16. 8 elems/thread.
__global__ __launch_bounds__(256) void attn_combine(const unsigned short* __restrict__ opart,
                                                    const float* __restrict__ rspart,
                                                    unsigned short* __restrict__ o) {
    int i = blockIdx.x * 256 + threadIdx.x;       // 524288 threads over [32][2048][64]
    int base = i * 8;
    int bh = base >> 17, m = (base >> 6) & 2047, d0 = base & 63;
    const unsigned short* o1 = opart + base;
    const unsigned short* o2 = opart + 32 * 2048 * 64 + base;
    float r = rspart[(bh << 11) + m] + rspart[(32 << 11) + (bh << 11) + m];
    float inv = 1.0f / r;
    ushort4 a0 = *(const ushort4*)o1, a1 = *(const ushort4*)(o1 + 4);
    ushort4 b0 = *(const ushort4*)o2, b1 = *(const ushort4*)(o2 + 4);
    unsigned short res[8];
    const unsigned short* ap = (const unsigned short*)&a0;
    const unsigned short* bp = (const unsigned short*)&b0;
#pragma unroll
    for (int j = 0; j < 8; j++) {
        unsigned short av = (j < 4) ? ((const unsigned short*)&a0)[j]
                                    : ((const unsigned short*)&a1)[j - 4];
        unsigned short bv = (j < 4) ? ((const unsigned short*)&b0)[j]
                                    : ((const unsigned short*)&b1)[j - 4];
        float fa = __builtin_bit_cast(float, (unsigned)av << 16);
        float fb = __builtin_bit_cast(float, (unsigned)bv << 16);
        res[j] = f2bf((fa + fb) * inv);
    }
    unsigned short* dst = o + ((size_t)((bh >> 4) * 2048 + m)) * 1024 + (bh & 15) * 64 + d0;
    *(ushort4*)dst = *(const ushort4*)&res[0];
    *(ushort4*)(dst + 4) = *(const ushort4*)&res[4];
    (void)ap; (void)bp;
}

// ---------------- launcher ----------------

extern "C" void kernel_launch(void* const* d_in, const int* in_sizes, int n_in,
                              void* d_out, int out_size, void* d_ws, size_t ws_size,
                              hipStream_t stream) {
    const float* x = (const float*)d_in[0];
    const float* w_qkv = (const float*)d_in[1];
    const float* w_out = (const float*)d_in[2];
    float* out = (float*)d_out;

    unsigned short* xb    = (unsigned short*)d_ws;        // 4096*1024
    unsigned short* wqkvT = xb + 4096 * 1024;             // 3072*1024
    unsigned short* woutT = wqkvT + 3072 * 1024;          // 1024*1024
    unsigned short* qb    = woutT + 1024 * 1024;          // 2*16*2048*64
    unsigned short* kb    = qb + 2 * 16 * 2048 * 64;
    unsigned short* vtb   = kb + 2 * 16 * 2048 * 64;
    unsigned short* ob    = vtb + 2 * 16 * 2048 * 64;     // 4096*1024
    float* cosT = (float*)(ob + 4096 * 1024);             // 2048*32 fp32
    float* sinT = cosT + 2048 * 32;
    unsigned short* opart = (unsigned short*)(sinT + 2048 * 32);  // 2*32*2048*64 bf16
    float* rspart = (float*)(opart + 2 * 32 * 2048 * 64);         // 2*32*2048 fp32

    rope_tab<<<256, 256, 0, stream>>>(cosT, sinT);
    cvt_bf16<<<4096, 256, 0, stream>>>(x, xb, 4096 * 1024);
    transpose_cvt<<<dim3(96, 32), 256, 0, stream>>>(w_qkv, wqkvT, 1024, 3072);
    transpose_cvt<<<dim3(32, 32), 256, 0, stream>>>(w_out, woutT, 1024, 1024);
    gemm_bt<0><<<dim3(24, 32), 256, 0, stream>>>(xb, wqkvT, 1024, 3072,
                                                 qb, kb, vtb, nullptr, cosT, sinT);
    attn_half<<<1024, 256, 0, stream>>>(qb, kb, vtb, opart, rspart);
    attn_combine<<<2048, 256, 0, stream>>>(opart, rspart, ob);
    gemm_bt<1><<<dim3(8, 32), 256, 0, stream>>>(ob, woutT, 1024, 1024,
                                                nullptr, nullptr, nullptr, out,
                                                nullptr, nullptr);
}